// Round 3
// baseline (3366.506 us; speedup 1.0000x reference)
//
#include <hip/hip_runtime.h>
#include <hip/hip_cooperative_groups.h>
#include <cmath>
#include <vector>

namespace cg = cooperative_groups;

#define B_ 64
#define NP 512   // N == M == 512, D == 2

constexpr float L2E  = 1.4426950408889634f;   // log2(e)
constexpr float LN2f = 0.6931471805599453f;

struct EpsList { float e[64]; };

__device__ __forceinline__ float exp2_fast(float v) {
#if __has_builtin(__builtin_amdgcn_exp2f)
    return __builtin_amdgcn_exp2f(v);
#else
    return exp2f(v);
#endif
}
__device__ __forceinline__ float log2_fast(float v) {
#if __has_builtin(__builtin_amdgcn_logf)
    return __builtin_amdgcn_logf(v);
#else
    return log2f(v);
#endif
}

// One cooperative kernel runs: init pass, n_eps averaging passes, final
// extrapolation pass, and the weighted reduction. Grid: B_*8 blocks x 256.
// q = blockIdx&7: q<4 -> f-side (rows over x, reduce over y), q>=4 -> g-side.
// rq = q&3 selects a 128-row quarter. oct = tid&7 owns j = oct (mod 8);
// tid>>3 owns 4 consecutive rows. All per-point staging data (coords, |y|^2,
// log-weights) and the own-side previous potential live in REGISTERS across
// all passes; only the other-side potential is re-read from global (L2) each
// pass, synchronized by one grid.sync() per pass.
__global__ __launch_bounds__(256) void sinkhorn_coop(
    const float* __restrict__ a, const float* __restrict__ x,
    const float* __restrict__ bb, const float* __restrict__ y,
    const float* __restrict__ w, float* __restrict__ out,
    float* __restrict__ fA, float* __restrict__ gA,
    float* __restrict__ fB, float* __restrict__ gB,
    float* __restrict__ partial, EpsList el, int n_eps)
{
    cg::grid_group grid = cg::this_grid();
    __shared__ float4 sd[NP];   // {y0, y1, shp, pad} per reduced-over point
    __shared__ float s_eps[64];

    const int b   = blockIdx.x >> 3;
    const int q   = blockIdx.x & 7;
    const bool gside = q >= 4;
    const int rq  = q & 3;
    const int tid = threadIdx.x;

    if (tid < 64) s_eps[tid] = el.e[tid];

    // ---- one-time staging into registers ----
    // reduced-over side: 2 points per thread
    const float2* oc2   = (const float2*)(gside ? (x + b * NP * 2) : (y + b * NP * 2));
    const float*  oprob = gside ? (a + b * NP) : (bb + b * NP);
    float cx[2], cy[2], n2s[2], olg[2];
    #pragma unroll
    for (int u = 0; u < 2; ++u) {
        int t = tid + u * 256;
        float2 c = oc2[t];
        cx[u] = c.x; cy[u] = c.y;
        n2s[u] = fmaf(c.y, c.y, c.x * c.x);
        olg[u] = L2E * logf(oprob[t]);
    }
    // row side: 4 rows per thread
    const int oct = tid & 7;
    const int rowbase = rq * 128 + (tid >> 3) * 4;
    const float* mcoord = gside ? (y + b * NP * 2) : (x + b * NP * 2);
    const float4 rc01 = *(const float4*)(mcoord + rowbase * 2);
    const float4 rc23 = *(const float4*)(mcoord + rowbase * 2 + 4);
    float x0[4] = {rc01.x, rc01.z, rc23.x, rc23.z};
    float x1[4] = {rc01.y, rc01.w, rc23.y, rc23.w};
    float half_n2[4];
    #pragma unroll
    for (int r = 0; r < 4; ++r) half_n2[r] = 0.5f * fmaf(x1[r], x1[r], x0[r] * x0[r]);

    const float* opotA = gside ? fA : gA;   // other-side potential, buffer A/B
    const float* opotB = gside ? fB : gB;
    float*       dstA  = gside ? gA : fA;   // own-side output, buffer A/B
    float*       dstB  = gside ? gB : fB;

    float pv[4];        // own-side previous potential (what we wrote last pass)
    int curA = 1;       // which buffer holds the current potentials

    __syncthreads();    // s_eps ready

    // passes: p==0 init (eps=e[0], no h-potential, direct write)
    //         p in [1, n_eps]: averaging passes with eps=e[p-1]
    //         p==n_eps+1: final extrapolation at eps=e[n_eps-1], direct write
    const int n_pass = n_eps + 2;
    for (int p = 0; p < n_pass; ++p) {
        const float eps = (p == 0) ? s_eps[0]
                        : (p <= n_eps ? s_eps[p - 1] : s_eps[n_eps - 1]);
        const float inv_eps = 1.0f / eps;
        const float ieL2E = inv_eps * L2E;
        const float nie   = -0.5f * ieL2E;

        // refresh shp for the reduced-over side
        const float* opot = (curA ? opotA : opotB) + b * NP;
        #pragma unroll
        for (int u = 0; u < 2; ++u) {
            int t = tid + u * 256;
            float h = olg[u];
            if (p != 0) h = fmaf(opot[t], ieL2E, h);
            sd[t] = make_float4(cx[u], cy[u], fmaf(nie, n2s[u], h), 0.0f);
        }
        __syncthreads();

        float x0p[4], x1p[4], m[4], s[4];
        #pragma unroll
        for (int r = 0; r < 4; ++r) {
            x0p[r] = x0[r] * ieL2E;
            x1p[r] = x1[r] * ieL2E;
            m[r] = -INFINITY;
            s[r] = 0.0f;
        }

        #pragma unroll 1
        for (int k = 0; k < 8; ++k) {
            float4 cj[8];
            #pragma unroll
            for (int u = 0; u < 8; ++u) cj[u] = sd[64 * k + 8 * u + oct];
            #pragma unroll
            for (int r = 0; r < 4; ++r) {
                float arg[8];
                #pragma unroll
                for (int u = 0; u < 8; ++u)
                    arg[u] = fmaf(x1p[r], cj[u].y, fmaf(x0p[r], cj[u].x, cj[u].z));
                float cm = fmaxf(fmaxf(fmaxf(arg[0], arg[1]), fmaxf(arg[2], arg[3])),
                                 fmaxf(fmaxf(arg[4], arg[5]), fmaxf(arg[6], arg[7])));
                float mn = fmaxf(m[r], cm);
                s[r] *= exp2_fast(m[r] - mn);   // first chunk: exp2(-inf)=0
                #pragma unroll
                for (int u = 0; u < 8; ++u) s[r] += exp2_fast(arg[u] - mn);
                m[r] = mn;
            }
        }

        // combine 8 octants via butterfly (all 8 lanes end with the result)
        float val[4];
        #pragma unroll
        for (int r = 0; r < 4; ++r) {
            float mr = m[r], sr = s[r];
            #pragma unroll
            for (int d = 1; d <= 4; d <<= 1) {
                float mo = __shfl_xor(mr, d);
                float so = __shfl_xor(sr, d);
                float mt = fmaxf(mr, mo);
                sr = sr * exp2_fast(mr - mt) + so * exp2_fast(mo - mt);
                mr = mt;
            }
            val[r] = fmaf(-eps * LN2f, mr + log2_fast(sr), half_n2[r]);
        }

        if (p >= 1 && p <= n_eps) {
            #pragma unroll
            for (int r = 0; r < 4; ++r) val[r] = 0.5f * (pv[r] + val[r]);
        }
        #pragma unroll
        for (int r = 0; r < 4; ++r) pv[r] = val[r];

        if (oct == 0) {
            float* dst = ((p == 0) ? dstA : (curA ? dstB : dstA)) + b * NP;
            *(float4*)(dst + rowbase) = make_float4(val[0], val[1], val[2], val[3]);
        }
        curA = (p == 0) ? 1 : !curA;
        grid.sync();
    }

    // ---- fused weighted reduction ----
    const float* ff = (curA ? fA : fB) + b * NP;
    const float* gg = (curA ? gA : gB) + b * NP;
    if (q == 0) {
        float sum = 0.0f;
        for (int t = tid; t < NP; t += 256)
            sum += a[b * NP + t] * ff[t] + bb[b * NP + t] * gg[t];
        #pragma unroll
        for (int o = 32; o > 0; o >>= 1) sum += __shfl_down(sum, o);
        float* red = (float*)sd;
        if ((tid & 63) == 0) red[tid >> 6] = sum;
        __syncthreads();
        if (tid == 0) partial[b] = w[b] * (red[0] + red[1] + red[2] + red[3]);
    }
    grid.sync();
    if (blockIdx.x == 0 && tid < 64) {
        float v = partial[tid];
        #pragma unroll
        for (int o = 32; o > 0; o >>= 1) v += __shfl_down(v, o);
        if (tid == 0) out[0] = v;
    }
}

extern "C" void kernel_launch(void* const* d_in, const int* in_sizes, int n_in,
                              void* d_out, int out_size, void* d_ws, size_t ws_size,
                              hipStream_t stream) {
    const float* a  = (const float*)d_in[0];  // prob1   [B,N]
    const float* x  = (const float*)d_in[1];  // coord1  [B,N,2]
    const float* bb = (const float*)d_in[2];  // prob2   [B,M]
    const float* y  = (const float*)d_in[3];  // coord2  [B,M,2]
    const float* w  = (const float*)d_in[4];  // weights [B]
    float* out = (float*)d_out;

    float* ws = (float*)d_ws;
    const int NB = B_ * NP;
    float* fA = ws;
    float* gA = fA + NB;
    float* fB = gA + NB;
    float* gB = fB + NB;
    float* partial = gB + NB;  // 64 floats

    // eps schedule (geomloss epsilon_schedule semantics, computed in double)
    EpsList el{};
    int n_eps = 0;
    {
        const double start = 2.0 * std::log(4.0);
        const double stop  = 2.0 * std::log(0.01);
        const double step  = 2.0 * std::log(0.9);
        el.e[n_eps++] = 16.0f;                     // DIAMETER**P
        for (int k = 0;; ++k) {
            double v = start + (double)k * step;
            if (!(v > stop)) break;
            el.e[n_eps++] = (float)std::exp(v);
        }
        el.e[n_eps++] = (float)(0.01 * 0.01);      // BLUR**P
    }

    void* args[] = {
        (void*)&a, (void*)&x, (void*)&bb, (void*)&y, (void*)&w, (void*)&out,
        (void*)&fA, (void*)&gA, (void*)&fB, (void*)&gB, (void*)&partial,
        (void*)&el, (void*)&n_eps
    };
    hipLaunchCooperativeKernel((const void*)sinkhorn_coop,
                               dim3(B_ * 8), dim3(256), args, 0, stream);
}